// Round 8
// baseline (77.404 us; speedup 1.0000x reference)
//
#include <hip/hip_runtime.h>

#define NB 64
#define NP 32768
#define NA 14
#define NC 10
#define NANCH (NB * NP)            // 2097152 anchors
#define TILE 256                   // anchors per LDS tile
#define TPB 8                      // tiles per block
#define MAIN_BLOCKS (NANCH / (TILE * TPB)) // 1024

// ws layout (doubles):
//   ws[0            .. MAIN_BLOCKS-1]   per-block loss partial
//   ws[MAIN_BLOCKS  .. 2*MAIN_BLOCKS-1] per-block pos-count partial
//   ws[ACC_LOSS]  base loss total (main winner writes on slow path)
//   ws[ACC_NPOS]  num_pos        (main winner writes)
//   ws[ACC_MINE]  mined-neg sum  (main winner zeroes on slow path)
//   ws[DONE_SLOT] main ticket u64   — MODULO ticket: winner is
//                 (val % MAIN_BLOCKS)==MAIN_BLOCKS-1, correct for ANY
//                 starting value -> no init needed, replay-safe.
//   ws[FIN_SLOT]  finish ticket u64 — same modulo trick with NB.
// No memset: every value read is either written earlier in the same launch
// or (tickets) is start-value-independent.
#define ACC_LOSS  (2 * MAIN_BLOCKS)
#define ACC_NPOS  (2 * MAIN_BLOCKS + 1)
#define ACC_MINE  (2 * MAIN_BLOCKS + 2)
#define DONE_SLOT (2 * MAIN_BLOCKS + 3)
#define FIN_SLOT  (2 * MAIN_BLOCKS + 4)

typedef const __attribute__((address_space(1))) void* gptr_t;
typedef __attribute__((address_space(3))) void* lptr_t;

__global__ __launch_bounds__(256) void ssd_main(
    const float* __restrict__ p,
    const float* __restrict__ loc_t,
    const int* __restrict__ conf_t,
    double* __restrict__ ws,
    float* __restrict__ out)
{
    // double-buffered p tiles: 2 x 256 anchors x 14 floats = 28672 B
    __shared__ float sp[2][TILE * NA];

    const int tid  = threadIdx.x;
    const int lane = tid & 63, wid = tid >> 6;
    const size_t tile0 = (size_t)blockIdx.x * TPB;

    // async global->LDS stage of one 14336B tile (896 x 16B chunks):
    // chunk c -> LDS byte c*16; wave-uniform LDS base, per-lane global src.
    auto stage = [&](int b, size_t tidx) {
        const char* gsrc  = reinterpret_cast<const char*>(p + tidx * (TILE * NA));
        char*       sbase = reinterpret_cast<char*>(sp[b]);
#pragma unroll
        for (int k = 0; k < 3; ++k) {
            const int c0 = k * 256 + wid * 64;        // wave-uniform
            __builtin_amdgcn_global_load_lds(
                (gptr_t)(gsrc + (size_t)(c0 + lane) * 16),
                (lptr_t)(sbase + (size_t)c0 * 16), 16, 0, 0);
        }
        if (wid < 2) {                                // tail 128 chunks
            const int c0 = 768 + wid * 64;
            __builtin_amdgcn_global_load_lds(
                (gptr_t)(gsrc + (size_t)(c0 + lane) * 16),
                (lptr_t)(sbase + (size_t)c0 * 16), 16, 0, 0);
        }
    };

    // prologue: tile 0's stage + per-anchor loads all in flight together
    stage(0, tile0);
    float4 ltc = reinterpret_cast<const float4*>(loc_t)[tile0 * TILE + tid];
    int    tc  = conf_t[tile0 * TILE + tid];

    float lossAcc = 0.f;
    int   cntAcc  = 0;

#pragma unroll
    for (int it = 0; it < TPB; ++it) {
        __syncthreads();   // drains stage(it) + ltc/tc (issued a full
                           // compute phase ago, except tile 0) and protects
                           // the buffer the next prefetch overwrites.

        // issue next tile's stage + per-anchor loads NOW, so the next
        // barrier never waits on a fresh load (async-STAGE split).
        float4 ltn = ltc; int tn = tc;
        if (it + 1 < TPB) {
            stage((it + 1) & 1, tile0 + it + 1);
            const size_t nb = (tile0 + it + 1) * TILE;
            ltn = reinterpret_cast<const float4*>(loc_t)[nb + tid];
            tn  = conf_t[nb + tid];
        }

        // ---- read own anchor row from LDS (8B-aligned float2 reads) ----
        const float2* row =
            reinterpret_cast<const float2*>(&sp[it & 1][tid * NA]);
        float x[14];
#pragma unroll
        for (int j = 0; j < 7; ++j) {
            float2 w = row[j];
            x[2 * j]     = w.x;
            x[2 * j + 1] = w.y;
        }

        // stable logsumexp over conf logits x[4..13]
        float m = x[4];
#pragma unroll
        for (int j = 5; j < 14; ++j) m = fmaxf(m, x[j]);
        float s = 0.f;
#pragma unroll
        for (int j = 4; j < 14; ++j) s += __expf(x[j] - m);
        float lse = m + __logf(s);

        // target logit via select chain (no runtime register indexing)
        float tgt = x[4];
#pragma unroll
        for (int j = 1; j < 10; ++j) tgt = (tc == j) ? x[4 + j] : tgt;
        float ce = lse - tgt;

        if (tc > 0) {
            float l = ce;
            const float* ltf = reinterpret_cast<const float*>(&ltc);
#pragma unroll
            for (int j = 0; j < 4; ++j) {
                float d  = x[j] - ltf[j];
                float ad = fabsf(d);
                l += (ad < 1.f) ? (0.5f * d * d) : (ad - 0.5f);
            }
            lossAcc += l;
            ++cntAcc;
        }
        ltc = ltn; tc = tn;
    }

    // ---- wave64 reduce in double, cross-wave via LDS ----
    double dl = (double)lossAcc;
    int cnt = cntAcc;
#pragma unroll
    for (int off = 32; off > 0; off >>= 1) {
        dl  += __shfl_down(dl, off, 64);
        cnt += __shfl_down(cnt, off, 64);
    }
    __shared__ double sL[4];
    __shared__ int    sC[4];
    if (lane == 0) { sL[wid] = dl; sC[wid] = cnt; }
    __syncthreads();

    // ---- store partial, modulo ticket; last block finishes inline ----
    __shared__ int s_winner;
    if (tid == 0) {
        ws[blockIdx.x] = sL[0] + sL[1] + sL[2] + sL[3];
        ws[MAIN_BLOCKS + blockIdx.x] =
            (double)(sC[0] + sC[1] + sC[2] + sC[3]);
        __threadfence();                       // release partials
        unsigned long long tkt = __hip_atomic_fetch_add(
            reinterpret_cast<unsigned long long*>(ws + DONE_SLOT), 1ull,
            __ATOMIC_ACQ_REL, __HIP_MEMORY_SCOPE_AGENT);
        s_winner = ((tkt & (unsigned long long)(MAIN_BLOCKS - 1)) ==
                    (unsigned long long)(MAIN_BLOCKS - 1));
    }
    __syncthreads();

    if (s_winner) {
        __threadfence();                       // acquire partials
        double l = 0.0, c = 0.0;
        for (int i = tid; i < MAIN_BLOCKS; i += 256) {
            l += ws[i];
            c += ws[MAIN_BLOCKS + i];
        }
#pragma unroll
        for (int off = 32; off > 0; off >>= 1) {
            l += __shfl_down(l, off, 64);
            c += __shfl_down(c, off, 64);
        }
        __shared__ double fL[4], fC[4];
        if (lane == 0) { fL[wid] = l; fC[wid] = c; }
        __syncthreads();
        if (tid == 0) {
            double L  = fL[0] + fL[1] + fL[2] + fL[3];
            double np = fC[0] + fC[1] + fC[2] + fC[3];
            ws[ACC_NPOS] = np;
            long long npi = (long long)np;
            long long nn = 3 * npi;
            long long ub = (long long)NP - npi;
            if (ub < nn) nn = ub;
            if (nn <= 0) {
                out[0] = (float)(L / np);      // <- bench path: done here
            } else {
                ws[ACC_LOSS] = L;
                ws[ACC_MINE] = 0.0;
            }
        }
    }
}

// loss_c for anchor i of a row: ce if negative anchor, else 0.
__device__ __forceinline__ float neg_conf_loss(
    const float* __restrict__ prow, const int* __restrict__ crow, int i)
{
    int t = crow[i];
    if (t > 0) return 0.f;
    const float* v = prow + (size_t)i * NA + 4;
    float m = v[0];
#pragma unroll
    for (int j = 1; j < NC; ++j) m = fmaxf(m, v[j]);
    float s = 0.f;
#pragma unroll
    for (int j = 0; j < NC; ++j) s += __expf(v[j] - m);
    return (m + __logf(s)) - v[0];   // t == 0 -> target logit is v[0]
}

// Slow-path-only hard-negative mining (fast path returns immediately):
// per-row radix-select top-nn, atomicAdd into ACC_MINE, modulo-ticketed
// last block combines with ACC_LOSS and writes out.
__global__ __launch_bounds__(256) void ssd_finish(
    const float* __restrict__ p,
    const int* __restrict__ conf_t,
    double* __restrict__ ws,
    float* __restrict__ out)
{
    const double np_d = ws[ACC_NPOS];
    long long np = (long long)np_d;
    long long nn = 3 * np;
    long long ub = (long long)NP - np;
    if (ub < nn) nn = ub;
    if (nn <= 0) return;                      // <- taken for bench inputs

    const int tid = threadIdx.x;
    const int lane = tid & 63, wid = tid >> 6;
    const float* prow = p + (size_t)blockIdx.x * NP * NA;
    const int*   crow = conf_t + (size_t)blockIdx.x * NP;

    __shared__ unsigned int hist[256];
    __shared__ unsigned int s_prefix;
    __shared__ long long    s_want;

    unsigned int prefix = 0;
    long long want = nn;                      // 1-indexed rank (largest)

    // 8-bit MSB-first radix select on float bits (loss_c >= 0 -> monotone).
    for (int pass = 0; pass < 4; ++pass) {
        int shift = 24 - 8 * pass;
        hist[tid] = 0;
        __syncthreads();
        for (int i = tid; i < NP; i += 256) {
            unsigned int k = __float_as_uint(neg_conf_loss(prow, crow, i));
            bool match = (pass == 0) || ((k >> (shift + 8)) == prefix);
            if (match) atomicAdd(&hist[(k >> shift) & 255u], 1u);
        }
        __syncthreads();
        if (tid == 0) {
            unsigned long long cum = 0;
            int d = 255;
            for (; d > 0; --d) {              // falls through to d=0
                unsigned long long h = hist[d];
                if (cum + h >= (unsigned long long)want) break;
                cum += h;
            }
            s_want   = want - (long long)cum;
            s_prefix = (prefix << 8) | (unsigned int)d;
        }
        __syncthreads();
        prefix = s_prefix;
        want   = s_want;
        __syncthreads();
    }

    float T = __uint_as_float(prefix);        // nn-th largest value
    double sgt = 0.0;
    long long cgt = 0;
    for (int i = tid; i < NP; i += 256) {
        float lc = neg_conf_loss(prow, crow, i);
        if (__float_as_uint(lc) > prefix) { sgt += (double)lc; ++cgt; }
    }
#pragma unroll
    for (int off = 32; off > 0; off >>= 1) {
        sgt += __shfl_down(sgt, off, 64);
        cgt += __shfl_down(cgt, off, 64);
    }
    __shared__ double    rL[4];
    __shared__ long long rC[4];
    if (lane == 0) { rL[wid] = sgt; rC[wid] = cgt; }
    __syncthreads();

    __shared__ int s_winner;
    if (tid == 0) {
        double stot = rL[0] + rL[1] + rL[2] + rL[3];
        long long ctot = rC[0] + rC[1] + rC[2] + rC[3];
        double rowsum = stot + (double)(nn - ctot) * (double)T;
        atomicAdd(&ws[ACC_MINE], rowsum);     // device-scope
        __threadfence();
        unsigned long long tkt = __hip_atomic_fetch_add(
            reinterpret_cast<unsigned long long*>(ws + FIN_SLOT), 1ull,
            __ATOMIC_ACQ_REL, __HIP_MEMORY_SCOPE_AGENT);
        s_winner = ((tkt & (unsigned long long)(NB - 1)) ==
                    (unsigned long long)(NB - 1));
    }
    __syncthreads();
    if (s_winner && tid == 0) {
        double base  = __hip_atomic_load(&ws[ACC_LOSS], __ATOMIC_RELAXED,
                                         __HIP_MEMORY_SCOPE_AGENT);
        double mined = __hip_atomic_load(&ws[ACC_MINE], __ATOMIC_RELAXED,
                                         __HIP_MEMORY_SCOPE_AGENT);
        out[0] = (float)((base + mined) / np_d);
    }
}

extern "C" void kernel_launch(void* const* d_in, const int* in_sizes, int n_in,
                              void* d_out, int out_size, void* d_ws, size_t ws_size,
                              hipStream_t stream)
{
    const float* p      = (const float*)d_in[0];
    const float* loc_t  = (const float*)d_in[1];
    const int*   conf_t = (const int*)d_in[2];
    float*  out = (float*)d_out;
    double* ws  = (double*)d_ws;

    ssd_main<<<MAIN_BLOCKS, 256, 0, stream>>>(p, loc_t, conf_t, ws, out);
    ssd_finish<<<NB, 256, 0, stream>>>(p, conf_t, ws, out);
}

// Round 9
// 32.962 us; speedup vs baseline: 2.3483x; 2.3483x over previous
//
#include <hip/hip_runtime.h>

#define NB 64
#define NP 32768
#define NA 14
#define NC 10
#define NANCH (NB * NP)            // 2097152 anchors
#define WAVES 4
#define WTILE 64                   // anchors per wave-tile (1 per lane)
#define TPW 8                      // tiles per wave
#define APB (WAVES * WTILE * TPW)  // anchors per block = 2048
#define MAIN_BLOCKS (NANCH / APB)  // 1024

// ws layout (doubles) — identical contract to the 33.57µs R7 version:
//   ws[0            .. MAIN_BLOCKS-1]   per-block loss partial
//   ws[MAIN_BLOCKS  .. 2*MAIN_BLOCKS-1] per-block pos-count partial
//   ws[ACC_LOSS]  base loss total   (finish block 0 writes on slow path)
//   ws[ACC_MINE]  mined-neg sum     (zeroed by main block0; slow path)
//   ws[DONE_SLOT] ticket u64        (zeroed by main block0; slow path only)
#define ACC_LOSS  (2 * MAIN_BLOCKS)
#define ACC_MINE  (2 * MAIN_BLOCKS + 1)
#define DONE_SLOT (2 * MAIN_BLOCKS + 2)

typedef const __attribute__((address_space(1))) void* gptr_t;
typedef __attribute__((address_space(3))) void* lptr_t;

// Barrier-free streaming main: each wave double-buffers its PRIVATE 3584B
// LDS slice (64 anchors x 56B) and orders stage->read with a counted
// per-wave s_waitcnt vmcnt(7). No __syncthreads in the loop, no fences,
// no atomics. Exactly 7 VMEM ops per iteration:
//   3x global_load_lds(16B) + 2x global_load_lds(4B) + lt float4 + conf int.
__global__ __launch_bounds__(256) void ssd_main(
    const float* __restrict__ p,
    const float* __restrict__ loc_t,
    const int* __restrict__ conf_t,
    double* __restrict__ ws)
{
    __shared__ float sp[2][WAVES][WTILE * NA];   // 2*4*896 floats = 28672 B

    const int tid  = threadIdx.x;
    const int lane = tid & 63, wid = tid >> 6;

    if (blockIdx.x == 0 && tid == 0) {
        ws[ACC_MINE] = 0.0;
        *reinterpret_cast<unsigned long long*>(ws + DONE_SLOT) = 0ull;
    }

    // wave-private anchor stream: anchors [wbase, wbase + 512)
    const size_t wbase = (size_t)blockIdx.x * APB + (size_t)wid * (WTILE * TPW);

    // stage tile t into buffer b: region = 224 x 16B chunks (3584 B)
    auto stage = [&](int b, int t) {
        const char* gsrc = reinterpret_cast<const char*>(
            p + (wbase + (size_t)t * WTILE) * NA);
        char* rb = reinterpret_cast<char*>(&sp[b][wid][0]);  // wave-uniform
#pragma unroll
        for (int k = 0; k < 3; ++k)              // chunks k*64+lane (192)
            __builtin_amdgcn_global_load_lds(
                (gptr_t)(gsrc + (size_t)(k * 64 + lane) * 16),
                (lptr_t)(rb + (size_t)k * 1024), 16, 0, 0);
#pragma unroll
        for (int k = 0; k < 2; ++k)              // tail 512 B as 2x4B/lane
            __builtin_amdgcn_global_load_lds(
                (gptr_t)(gsrc + 3072 + (size_t)k * 256 + (size_t)lane * 4),
                (lptr_t)(rb + 3072 + (size_t)k * 256), 4, 0, 0);
    };

    // prologue: tile 0 stage + its per-anchor loads (7 VMEM)
    stage(0, 0);
    float4 ltc = reinterpret_cast<const float4*>(loc_t)[wbase + lane];
    int    tc  = conf_t[wbase + lane];

    float lossAcc = 0.f;
    int   cntAcc  = 0;

#pragma unroll
    for (int it = 0; it < TPW; ++it) {
        // issue next tile's 7 VMEM ops, then wait only the PREVIOUS 7.
        float4 ltn = ltc; int tn = tc;
        if (it + 1 < TPW) {
            stage((it + 1) & 1, it + 1);
            const size_t na = wbase + (size_t)(it + 1) * WTILE + lane;
            ltn = reinterpret_cast<const float4*>(loc_t)[na];
            tn  = conf_t[na];
            __builtin_amdgcn_sched_barrier(0);
            asm volatile("s_waitcnt vmcnt(7)" ::: "memory");
            __builtin_amdgcn_sched_barrier(0);
        } else {
            __builtin_amdgcn_sched_barrier(0);
            asm volatile("s_waitcnt vmcnt(0)" ::: "memory");
            __builtin_amdgcn_sched_barrier(0);
        }

        // own anchor row from this wave's LDS slice (8B-aligned float2)
        const float2* row = reinterpret_cast<const float2*>(
            &sp[it & 1][wid][lane * NA]);
        float x[14];
#pragma unroll
        for (int j = 0; j < 7; ++j) {
            float2 w = row[j];
            x[2 * j]     = w.x;
            x[2 * j + 1] = w.y;
        }

        // stable logsumexp over conf logits x[4..13]
        float m = x[4];
#pragma unroll
        for (int j = 5; j < 14; ++j) m = fmaxf(m, x[j]);
        float s = 0.f;
#pragma unroll
        for (int j = 4; j < 14; ++j) s += __expf(x[j] - m);
        float lse = m + __logf(s);

        // target logit via select chain (no runtime register indexing)
        float tgt = x[4];
#pragma unroll
        for (int j = 1; j < 10; ++j) tgt = (tc == j) ? x[4 + j] : tgt;
        float ce = lse - tgt;

        if (tc > 0) {
            float l = ce;
            const float* ltf = reinterpret_cast<const float*>(&ltc);
#pragma unroll
            for (int j = 0; j < 4; ++j) {
                float d  = x[j] - ltf[j];
                float ad = fabsf(d);
                l += (ad < 1.f) ? (0.5f * d * d) : (ad - 0.5f);
            }
            lossAcc += l;
            ++cntAcc;
        }
        ltc = ltn; tc = tn;
    }

    // ---- wave64 reduce in double, cross-wave via LDS, 1 STORE per block ----
    double dl = (double)lossAcc;
    int cnt = cntAcc;
#pragma unroll
    for (int off = 32; off > 0; off >>= 1) {
        dl  += __shfl_down(dl, off, 64);
        cnt += __shfl_down(cnt, off, 64);
    }
    __shared__ double sL[4];
    __shared__ int    sC[4];
    if (lane == 0) { sL[wid] = dl; sC[wid] = cnt; }
    __syncthreads();
    if (tid == 0) {
        ws[blockIdx.x] = sL[0] + sL[1] + sL[2] + sL[3];
        ws[MAIN_BLOCKS + blockIdx.x] =
            (double)(sC[0] + sC[1] + sC[2] + sC[3]);
    }
}

// loss_c for anchor i of a row: ce if negative anchor, else 0.
__device__ __forceinline__ float neg_conf_loss(
    const float* __restrict__ prow, const int* __restrict__ crow, int i)
{
    int t = crow[i];
    if (t > 0) return 0.f;
    const float* v = prow + (size_t)i * NA + 4;
    float m = v[0];
#pragma unroll
    for (int j = 1; j < NC; ++j) m = fmaxf(m, v[j]);
    float s = 0.f;
#pragma unroll
    for (int j = 0; j < NC; ++j) s += __expf(v[j] - m);
    return (m + __logf(s)) - v[0];   // t == 0 -> target logit is v[0]
}

// Fused tail (64 blocks), identical to the proven R7 version: every block
// reduces the count partials (8 KB). Fast path (num_neg<=0, bench inputs):
// block 0 reduces the loss partials and writes out; no fences/tickets.
// Slow path: per-row radix-select mining + ticketed combine.
__global__ __launch_bounds__(256) void ssd_finish(
    const float* __restrict__ p,
    const int* __restrict__ conf_t,
    double* __restrict__ ws,
    float* __restrict__ out)
{
    const int tid = threadIdx.x;
    const int lane = tid & 63, wid = tid >> 6;
    __shared__ double sR[4];
    __shared__ double s_np;

    // ---- 1. num_pos (identical in every block) ----
    double c = 0.0;
    for (int i = tid; i < MAIN_BLOCKS; i += 256)
        c += ws[MAIN_BLOCKS + i];
#pragma unroll
    for (int off = 32; off > 0; off >>= 1)
        c += __shfl_down(c, off, 64);
    if (lane == 0) sR[wid] = c;
    __syncthreads();
    if (tid == 0) s_np = sR[0] + sR[1] + sR[2] + sR[3];
    __syncthreads();
    const double np_d = s_np;

    long long np = (long long)np_d;
    long long nn = 3 * np;
    long long ub = (long long)NP - np;
    if (ub < nn) nn = ub;

    auto base_loss = [&]() -> double {          // reduce loss partials
        double l = 0.0;
        for (int i = tid; i < MAIN_BLOCKS; i += 256)
            l += ws[i];
#pragma unroll
        for (int off = 32; off > 0; off >>= 1)
            l += __shfl_down(l, off, 64);
        __shared__ double fL[4];
        if (lane == 0) fL[wid] = l;
        __syncthreads();
        return fL[0] + fL[1] + fL[2] + fL[3];   // valid in tid 0
    };

    if (nn <= 0) {                              // <- bench path
        if (blockIdx.x == 0) {
            double L = base_loss();
            if (tid == 0) out[0] = (float)(L / np_d);
        }
        return;
    }

    // ---- 2. slow path: mine this block's row ----
    const float* prow = p + (size_t)blockIdx.x * NP * NA;
    const int*   crow = conf_t + (size_t)blockIdx.x * NP;

    __shared__ unsigned int hist[256];
    __shared__ unsigned int s_prefix;
    __shared__ long long    s_want;

    unsigned int prefix = 0;
    long long want = nn;                        // 1-indexed rank (largest)

    // 8-bit MSB-first radix select on float bits (loss_c >= 0 -> monotone).
    for (int pass = 0; pass < 4; ++pass) {
        int shift = 24 - 8 * pass;
        hist[tid] = 0;
        __syncthreads();
        for (int i = tid; i < NP; i += 256) {
            unsigned int k = __float_as_uint(neg_conf_loss(prow, crow, i));
            bool match = (pass == 0) || ((k >> (shift + 8)) == prefix);
            if (match) atomicAdd(&hist[(k >> shift) & 255u], 1u);
        }
        __syncthreads();
        if (tid == 0) {
            unsigned long long cum = 0;
            int d = 255;
            for (; d > 0; --d) {                // falls through to d=0
                unsigned long long h = hist[d];
                if (cum + h >= (unsigned long long)want) break;
                cum += h;
            }
            s_want   = want - (long long)cum;
            s_prefix = (prefix << 8) | (unsigned int)d;
        }
        __syncthreads();
        prefix = s_prefix;
        want   = s_want;
        __syncthreads();
    }

    float T = __uint_as_float(prefix);          // nn-th largest value
    double sgt = 0.0;
    long long cgt = 0;
    for (int i = tid; i < NP; i += 256) {
        float lc = neg_conf_loss(prow, crow, i);
        if (__float_as_uint(lc) > prefix) { sgt += (double)lc; ++cgt; }
    }
#pragma unroll
    for (int off = 32; off > 0; off >>= 1) {
        sgt += __shfl_down(sgt, off, 64);
        cgt += __shfl_down(cgt, off, 64);
    }
    __shared__ double    rL[4];
    __shared__ long long rC[4];
    if (lane == 0) { rL[wid] = sgt; rC[wid] = cgt; }
    __syncthreads();
    if (tid == 0) {
        double stot = rL[0] + rL[1] + rL[2] + rL[3];
        long long ctot = rC[0] + rC[1] + rC[2] + rC[3];
        double rowsum = stot + (double)(nn - ctot) * (double)T;
        atomicAdd(&ws[ACC_MINE], rowsum);       // device-scope
    }

    if (blockIdx.x == 0) {                      // base loss alongside mining
        double L = base_loss();
        if (tid == 0) ws[ACC_LOSS] = L;
    }

    // ticket: last block combines and writes out (slow path only)
    __threadfence();
    __shared__ unsigned int s_ticket;
    if (tid == 0)
        s_ticket = atomicAdd(reinterpret_cast<unsigned int*>(ws + DONE_SLOT), 1u);
    __syncthreads();
    if (s_ticket == NB - 1 && tid == 0) {
        double base  = __hip_atomic_load(&ws[ACC_LOSS], __ATOMIC_RELAXED,
                                         __HIP_MEMORY_SCOPE_AGENT);
        double mined = __hip_atomic_load(&ws[ACC_MINE], __ATOMIC_RELAXED,
                                         __HIP_MEMORY_SCOPE_AGENT);
        out[0] = (float)((base + mined) / np_d);
    }
}

extern "C" void kernel_launch(void* const* d_in, const int* in_sizes, int n_in,
                              void* d_out, int out_size, void* d_ws, size_t ws_size,
                              hipStream_t stream)
{
    const float* p      = (const float*)d_in[0];
    const float* loc_t  = (const float*)d_in[1];
    const int*   conf_t = (const int*)d_in[2];
    float*  out = (float*)d_out;
    double* ws  = (double*)d_ws;

    ssd_main<<<MAIN_BLOCKS, 256, 0, stream>>>(p, loc_t, conf_t, ws);
    ssd_finish<<<NB, 256, 0, stream>>>(p, conf_t, ws, out);
}

// Round 10
// 31.681 us; speedup vs baseline: 2.4433x; 1.0404x over previous
//
#include <hip/hip_runtime.h>

#define NB 64
#define NP 32768
#define NA 14
#define NC 10
#define NANCH (NB * NP)            // 2097152 anchors
#define WAVES 4
#define WTILE 64                   // anchors per wave-tile (1 per lane)
#define TPW 8                      // tiles per wave
#define APB (WAVES * WTILE * TPW)  // anchors per block = 2048
#define MAIN_BLOCKS (NANCH / APB)  // 1024

// ws layout (doubles) — identical contract to the R9 (32.96µs) version:
//   ws[0            .. MAIN_BLOCKS-1]   per-block loss partial
//   ws[MAIN_BLOCKS  .. 2*MAIN_BLOCKS-1] per-block pos-count partial
//   ws[ACC_LOSS]  base loss total   (finish block 0 writes on slow path)
//   ws[ACC_MINE]  mined-neg sum     (zeroed by main block0; slow path)
//   ws[DONE_SLOT] ticket u64        (zeroed by main block0; slow path only)
#define ACC_LOSS  (2 * MAIN_BLOCKS)
#define ACC_MINE  (2 * MAIN_BLOCKS + 1)
#define DONE_SLOT (2 * MAIN_BLOCKS + 2)

typedef const __attribute__((address_space(1))) void* gptr_t;
typedef __attribute__((address_space(3))) void* lptr_t;

// Barrier-free streaming main: each wave double-buffers its PRIVATE 3584B
// LDS slice (64 anchors x 56B) and orders stage->read with a counted
// per-wave s_waitcnt vmcnt(6). No __syncthreads in the loop, no fences,
// no atomics. Exactly 6 VMEM ops per iteration:
//   3x full-wave global_load_lds(16B) + 1x half-wave global_load_lds(16B)
//   + lt float4 + conf int.
__global__ __launch_bounds__(256) void ssd_main(
    const float* __restrict__ p,
    const float* __restrict__ loc_t,
    const int* __restrict__ conf_t,
    double* __restrict__ ws)
{
    __shared__ float sp[2][WAVES][WTILE * NA];   // 2*4*896 floats = 28672 B

    const int tid  = threadIdx.x;
    const int lane = tid & 63, wid = tid >> 6;

    if (blockIdx.x == 0 && tid == 0) {
        ws[ACC_MINE] = 0.0;
        *reinterpret_cast<unsigned long long*>(ws + DONE_SLOT) = 0ull;
    }

    // wave-private anchor stream: anchors [wbase, wbase + 512)
    const size_t wbase = (size_t)blockIdx.x * APB + (size_t)wid * (WTILE * TPW);

    // stage tile t into buffer b: 3584 B = 3x64 + 1x32(masked) 16B chunks
    auto stage = [&](int b, int t) {
        const char* gsrc = reinterpret_cast<const char*>(
            p + (wbase + (size_t)t * WTILE) * NA);
        char* rb = reinterpret_cast<char*>(&sp[b][wid][0]);  // wave-uniform
#pragma unroll
        for (int k = 0; k < 3; ++k)              // chunks k*64+lane (192)
            __builtin_amdgcn_global_load_lds(
                (gptr_t)(gsrc + (size_t)(k * 64 + lane) * 16),
                (lptr_t)(rb + (size_t)k * 1024), 16, 0, 0);
        if (lane < 32)                           // tail 512 B, half wave
            __builtin_amdgcn_global_load_lds(
                (gptr_t)(gsrc + 3072 + (size_t)lane * 16),
                (lptr_t)(rb + 3072), 16, 0, 0);
    };

    // prologue: tile 0 stage + its per-anchor loads (6 VMEM)
    stage(0, 0);
    float4 ltc = reinterpret_cast<const float4*>(loc_t)[wbase + lane];
    int    tc  = conf_t[wbase + lane];

    float lossAcc = 0.f;
    int   cntAcc  = 0;

#pragma unroll
    for (int it = 0; it < TPW; ++it) {
        // issue next tile's 6 VMEM ops, then wait only the PREVIOUS 6.
        float4 ltn = ltc; int tn = tc;
        if (it + 1 < TPW) {
            stage((it + 1) & 1, it + 1);
            const size_t na = wbase + (size_t)(it + 1) * WTILE + lane;
            ltn = reinterpret_cast<const float4*>(loc_t)[na];
            tn  = conf_t[na];
            __builtin_amdgcn_sched_barrier(0);
            asm volatile("s_waitcnt vmcnt(6)" ::: "memory");
            __builtin_amdgcn_sched_barrier(0);
        } else {
            __builtin_amdgcn_sched_barrier(0);
            asm volatile("s_waitcnt vmcnt(0)" ::: "memory");
            __builtin_amdgcn_sched_barrier(0);
        }

        // own anchor row from this wave's LDS slice (8B-aligned float2)
        const float2* row = reinterpret_cast<const float2*>(
            &sp[it & 1][wid][lane * NA]);
        float x[14];
#pragma unroll
        for (int j = 0; j < 7; ++j) {
            float2 w = row[j];
            x[2 * j]     = w.x;
            x[2 * j + 1] = w.y;
        }

        // stable logsumexp over conf logits x[4..13]
        float m = x[4];
#pragma unroll
        for (int j = 5; j < 14; ++j) m = fmaxf(m, x[j]);
        float s = 0.f;
#pragma unroll
        for (int j = 4; j < 14; ++j) s += __expf(x[j] - m);
        float lse = m + __logf(s);

        // target logit via select chain (no runtime register indexing)
        float tgt = x[4];
#pragma unroll
        for (int j = 1; j < 10; ++j) tgt = (tc == j) ? x[4 + j] : tgt;
        float ce = lse - tgt;

        if (tc > 0) {
            float l = ce;
            const float* ltf = reinterpret_cast<const float*>(&ltc);
#pragma unroll
            for (int j = 0; j < 4; ++j) {
                float d  = x[j] - ltf[j];
                float ad = fabsf(d);
                l += (ad < 1.f) ? (0.5f * d * d) : (ad - 0.5f);
            }
            lossAcc += l;
            ++cntAcc;
        }
        ltc = ltn; tc = tn;
    }

    // ---- wave64 reduce in double, cross-wave via LDS, 1 STORE per block ----
    double dl = (double)lossAcc;
    int cnt = cntAcc;
#pragma unroll
    for (int off = 32; off > 0; off >>= 1) {
        dl  += __shfl_down(dl, off, 64);
        cnt += __shfl_down(cnt, off, 64);
    }
    __shared__ double sL[4];
    __shared__ int    sC[4];
    if (lane == 0) { sL[wid] = dl; sC[wid] = cnt; }
    __syncthreads();
    if (tid == 0) {
        ws[blockIdx.x] = sL[0] + sL[1] + sL[2] + sL[3];
        ws[MAIN_BLOCKS + blockIdx.x] =
            (double)(sC[0] + sC[1] + sC[2] + sC[3]);
    }
}

// loss_c for anchor i of a row: ce if negative anchor, else 0.
__device__ __forceinline__ float neg_conf_loss(
    const float* __restrict__ prow, const int* __restrict__ crow, int i)
{
    int t = crow[i];
    if (t > 0) return 0.f;
    const float* v = prow + (size_t)i * NA + 4;
    float m = v[0];
#pragma unroll
    for (int j = 1; j < NC; ++j) m = fmaxf(m, v[j]);
    float s = 0.f;
#pragma unroll
    for (int j = 0; j < NC; ++j) s += __expf(v[j] - m);
    return (m + __logf(s)) - v[0];   // t == 0 -> target logit is v[0]
}

// Fused tail (64 blocks): every block reduces the count partials (8 KB,
// double2-vectorized -> 2 latency rounds). Fast path (num_neg<=0, bench
// inputs): block 0 reduces the loss partials and writes out; no fences or
// tickets. Slow path: per-row radix-select mining + ticketed combine.
__global__ __launch_bounds__(256) void ssd_finish(
    const float* __restrict__ p,
    const int* __restrict__ conf_t,
    double* __restrict__ ws,
    float* __restrict__ out)
{
    const int tid = threadIdx.x;
    const int lane = tid & 63, wid = tid >> 6;
    __shared__ double sR[4];
    __shared__ double s_np;

    // ---- 1. num_pos (identical in every block), double2 loads ----
    double c = 0.0;
    {
        const double2* cp = reinterpret_cast<const double2*>(ws + MAIN_BLOCKS);
#pragma unroll
        for (int k = 0; k < MAIN_BLOCKS / 512; ++k) {
            double2 v = cp[tid + k * 256];
            c += v.x + v.y;
        }
    }
#pragma unroll
    for (int off = 32; off > 0; off >>= 1)
        c += __shfl_down(c, off, 64);
    if (lane == 0) sR[wid] = c;
    __syncthreads();
    if (tid == 0) s_np = sR[0] + sR[1] + sR[2] + sR[3];
    __syncthreads();
    const double np_d = s_np;

    long long np = (long long)np_d;
    long long nn = 3 * np;
    long long ub = (long long)NP - np;
    if (ub < nn) nn = ub;

    auto base_loss = [&]() -> double {          // reduce loss partials
        double l = 0.0;
        const double2* lp = reinterpret_cast<const double2*>(ws);
#pragma unroll
        for (int k = 0; k < MAIN_BLOCKS / 512; ++k) {
            double2 v = lp[tid + k * 256];
            l += v.x + v.y;
        }
#pragma unroll
        for (int off = 32; off > 0; off >>= 1)
            l += __shfl_down(l, off, 64);
        __shared__ double fL[4];
        if (lane == 0) fL[wid] = l;
        __syncthreads();
        return fL[0] + fL[1] + fL[2] + fL[3];   // valid in tid 0
    };

    if (nn <= 0) {                              // <- bench path
        if (blockIdx.x == 0) {
            double L = base_loss();
            if (tid == 0) out[0] = (float)(L / np_d);
        }
        return;
    }

    // ---- 2. slow path: mine this block's row ----
    const float* prow = p + (size_t)blockIdx.x * NP * NA;
    const int*   crow = conf_t + (size_t)blockIdx.x * NP;

    __shared__ unsigned int hist[256];
    __shared__ unsigned int s_prefix;
    __shared__ long long    s_want;

    unsigned int prefix = 0;
    long long want = nn;                        // 1-indexed rank (largest)

    // 8-bit MSB-first radix select on float bits (loss_c >= 0 -> monotone).
    for (int pass = 0; pass < 4; ++pass) {
        int shift = 24 - 8 * pass;
        hist[tid] = 0;
        __syncthreads();
        for (int i = tid; i < NP; i += 256) {
            unsigned int k = __float_as_uint(neg_conf_loss(prow, crow, i));
            bool match = (pass == 0) || ((k >> (shift + 8)) == prefix);
            if (match) atomicAdd(&hist[(k >> shift) & 255u], 1u);
        }
        __syncthreads();
        if (tid == 0) {
            unsigned long long cum = 0;
            int d = 255;
            for (; d > 0; --d) {                // falls through to d=0
                unsigned long long h = hist[d];
                if (cum + h >= (unsigned long long)want) break;
                cum += h;
            }
            s_want   = want - (long long)cum;
            s_prefix = (prefix << 8) | (unsigned int)d;
        }
        __syncthreads();
        prefix = s_prefix;
        want   = s_want;
        __syncthreads();
    }

    float T = __uint_as_float(prefix);          // nn-th largest value
    double sgt = 0.0;
    long long cgt = 0;
    for (int i = tid; i < NP; i += 256) {
        float lc = neg_conf_loss(prow, crow, i);
        if (__float_as_uint(lc) > prefix) { sgt += (double)lc; ++cgt; }
    }
#pragma unroll
    for (int off = 32; off > 0; off >>= 1) {
        sgt += __shfl_down(sgt, off, 64);
        cgt += __shfl_down(cgt, off, 64);
    }
    __shared__ double    rL[4];
    __shared__ long long rC[4];
    if (lane == 0) { rL[wid] = sgt; rC[wid] = cgt; }
    __syncthreads();
    if (tid == 0) {
        double stot = rL[0] + rL[1] + rL[2] + rL[3];
        long long ctot = rC[0] + rC[1] + rC[2] + rC[3];
        double rowsum = stot + (double)(nn - ctot) * (double)T;
        atomicAdd(&ws[ACC_MINE], rowsum);       // device-scope
    }

    if (blockIdx.x == 0) {                      // base loss alongside mining
        double L = base_loss();
        if (tid == 0) ws[ACC_LOSS] = L;
    }

    // ticket: last block combines and writes out (slow path only)
    __threadfence();
    __shared__ unsigned int s_ticket;
    if (tid == 0)
        s_ticket = atomicAdd(reinterpret_cast<unsigned int*>(ws + DONE_SLOT), 1u);
    __syncthreads();
    if (s_ticket == NB - 1 && tid == 0) {
        double base  = __hip_atomic_load(&ws[ACC_LOSS], __ATOMIC_RELAXED,
                                         __HIP_MEMORY_SCOPE_AGENT);
        double mined = __hip_atomic_load(&ws[ACC_MINE], __ATOMIC_RELAXED,
                                         __HIP_MEMORY_SCOPE_AGENT);
        out[0] = (float)((base + mined) / np_d);
    }
}

extern "C" void kernel_launch(void* const* d_in, const int* in_sizes, int n_in,
                              void* d_out, int out_size, void* d_ws, size_t ws_size,
                              hipStream_t stream)
{
    const float* p      = (const float*)d_in[0];
    const float* loc_t  = (const float*)d_in[1];
    const int*   conf_t = (const int*)d_in[2];
    float*  out = (float*)d_out;
    double* ws  = (double*)d_ws;

    ssd_main<<<MAIN_BLOCKS, 256, 0, stream>>>(p, loc_t, conf_t, ws);
    ssd_finish<<<NB, 256, 0, stream>>>(p, conf_t, ws, out);
}